// Round 3
// baseline (74.733 us; speedup 1.0000x reference)
//
#include <hip/hip_runtime.h>

#define NB 65536
#define NJ 24
#define NTRK 6
#define BPB 8      // batches per 256-thread block
#define GRP 32     // lanes per batch group (24 active)

typedef float f4 __attribute__((ext_vector_type(4)));

__device__ __forceinline__ void rpy2R(float r, float p, float y, float* R) {
    float cr = cosf(r), sr = sinf(r);
    float cp = cosf(p), sp = sinf(p);
    float cy = cosf(y), sy = sinf(y);
    R[0] = cy * cp; R[1] = cy * sp * sr - sy * cr; R[2] = cy * sp * cr + sy * sr;
    R[3] = sy * cp; R[4] = sy * sp * sr + cy * cr; R[5] = sy * sp * cr - cy * sr;
    R[6] = -sp;     R[7] = cp * sr;                R[8] = cp * cr;
}

// C = A o B (SE3): Rc = Ra*Rb, pc = Ra*pb + pa.  C must not alias A or B.
__device__ __forceinline__ void compose(const float* Ra, const float* pa,
                                        const float* Rb, const float* pb,
                                        float* Rc, float* pc) {
#pragma unroll
    for (int i = 0; i < 3; i++) {
        float a0 = Ra[i*3+0], a1 = Ra[i*3+1], a2 = Ra[i*3+2];
        Rc[i*3+0] = a0*Rb[0] + a1*Rb[3] + a2*Rb[6];
        Rc[i*3+1] = a0*Rb[1] + a1*Rb[4] + a2*Rb[7];
        Rc[i*3+2] = a0*Rb[2] + a1*Rb[5] + a2*Rb[8];
        pc[i]     = a0*pb[0] + a1*pb[1] + a2*pb[2] + pa[i];
    }
}

// ---- one-block precompute of per-joint statics into d_ws ----
// layout per joint j (float4 index j*8 + k):
//   0..2: T_offset rows (R row | p component)
//   3:    normalized rev axis (ax,ay,az,adot)
//   4:    pri_axis (x,y,z,0)
//   5..7: T_track rows (R row | p component)
__global__ void statics_kernel(
    const float* __restrict__ p_off,    const float* __restrict__ rpy_off,
    const float* __restrict__ rev_axis, const float* __restrict__ pri_axis,
    const float* __restrict__ p_trk,    const float* __restrict__ rpy_trk,
    float4* __restrict__ ws)
{
    int j = threadIdx.x;
    if (j >= NJ) return;
    float R[9];
    rpy2R(rpy_off[j*3+0], rpy_off[j*3+1], rpy_off[j*3+2], R);
    ws[j*8+0] = make_float4(R[0], R[1], R[2], p_off[j*3+0]);
    ws[j*8+1] = make_float4(R[3], R[4], R[5], p_off[j*3+1]);
    ws[j*8+2] = make_float4(R[6], R[7], R[8], p_off[j*3+2]);

    float ax = rev_axis[j*3+0], ay = rev_axis[j*3+1], az = rev_axis[j*3+2];
    float n = sqrtf(ax*ax + ay*ay + az*az) + 1e-8f;   // ref: axis/(norm+EPS)
    ax /= n; ay /= n; az /= n;
    ws[j*8+3] = make_float4(ax, ay, az, ax*ax + ay*ay + az*az);
    ws[j*8+4] = make_float4(pri_axis[j*3+0], pri_axis[j*3+1], pri_axis[j*3+2], 0.f);

    rpy2R(rpy_trk[j*3+0], rpy_trk[j*3+1], rpy_trk[j*3+2], R);
    ws[j*8+5] = make_float4(R[0], R[1], R[2], p_trk[j*3+0]);
    ws[j*8+6] = make_float4(R[3], R[4], R[5], p_trk[j*3+1]);
    ws[j*8+7] = make_float4(R[6], R[7], R[8], p_trk[j*3+2]);
}

__global__ __launch_bounds__(256, 4) void fk_scan_kernel(
    const float* __restrict__ rev_q, const float* __restrict__ pri_q,
    const float4* __restrict__ stat,
    float* __restrict__ out_track, float* __restrict__ out_joint)
{
    __shared__ float s_j[BPB * NJ * 16];    // 12 KB, exact output layout
    __shared__ float s_t[BPB * NTRK * 16];  //  3 KB

    const int tid = threadIdx.x;
    const int g   = tid & (GRP - 1);          // lane within batch group
    const int bl  = tid >> 5;                 // batch within block
    const int b   = blockIdx.x * BPB + bl;
    const int j   = (g < NJ) ? g : (NJ - 1);  // clamp padding lanes (no OOB)
    const bool active = (g < NJ);

    // stream-once q values: nontemporal, issued first to overlap
    float qr = __builtin_nontemporal_load(rev_q + (size_t)b * NJ + j);
    float qp = __builtin_nontemporal_load(pri_q + (size_t)b * NJ + j);

    // per-joint statics: 5 coalesced float4 loads from hot 3KB ws block
    const float4 s0 = stat[j*8+0], s1 = stat[j*8+1], s2 = stat[j*8+2];
    const float4 s3 = stat[j*8+3], s4 = stat[j*8+4];
    float ToR[9] = {s0.x,s0.y,s0.z, s1.x,s1.y,s1.z, s2.x,s2.y,s2.z};
    float Top[3] = {s0.w, s1.w, s2.w};
    const float ax = s3.x, ay = s3.y, az = s3.z, adot = s3.w;

    // ---- per-(b,j) joint transform Tj (Rodrigues + prismatic) ----
    float s = __sinf(qr), c = __cosf(qr), c1 = 1.0f - c;
    float jR[9];
    jR[0] = 1.f + c1*(ax*ax - adot);  jR[1] = -s*az + c1*ax*ay;        jR[2] =  s*ay + c1*ax*az;
    jR[3] =  s*az + c1*ax*ay;         jR[4] = 1.f + c1*(ay*ay - adot); jR[5] = -s*ax + c1*ay*az;
    jR[6] = -s*ay + c1*ax*az;         jR[7] =  s*ax + c1*ay*az;        jR[8] = 1.f + c1*(az*az - adot);
    float v0 = qp * s4.x, v1 = qp * s4.y, v2 = qp * s4.z;
    float jp[3];
    jp[0] = jR[0]*v0 + jR[1]*v1 + jR[2]*v2;
    jp[1] = jR[3]*v0 + jR[4]*v1 + jR[5]*v2;
    jp[2] = jR[6]*v0 + jR[7]*v1 + jR[8]*v2;

    // ---- L_j = T_offset[j] o T_joint[j];  M = inclusive prefix product ----
    float MR[9], Mp[3];
    compose(ToR, Top, jR, jp, MR, Mp);

#pragma unroll
    for (int sft = 1; sft < NJ; sft <<= 1) {   // 1,2,4,8,16
        float fR[9], fp[3];
#pragma unroll
        for (int k = 0; k < 9; k++) fR[k] = __shfl_up(MR[k], sft, GRP);
#pragma unroll
        for (int k = 0; k < 3; k++) fp[k] = __shfl_up(Mp[k], sft, GRP);
        if (g >= sft) {
            float nR[9], np[3];
            compose(fR, fp, MR, Mp, nR, np);   // earlier-index operand on the left
#pragma unroll
            for (int k = 0; k < 9; k++) MR[k] = nR[k];
#pragma unroll
            for (int k = 0; k < 3; k++) Mp[k] = np[k];
        }
    }

    // ---- exclusive prefix E = M_{j-1} (identity at j=0) ----
    float ER[9], Ep[3];
#pragma unroll
    for (int k = 0; k < 9; k++) ER[k] = __shfl_up(MR[k], 1, GRP);
#pragma unroll
    for (int k = 0; k < 3; k++) Ep[k] = __shfl_up(Mp[k], 1, GRP);
    if (g == 0) {
        ER[0]=1.f; ER[1]=0.f; ER[2]=0.f; ER[3]=0.f; ER[4]=1.f; ER[5]=0.f;
        ER[6]=0.f; ER[7]=0.f; ER[8]=1.f; Ep[0]=0.f; Ep[1]=0.f; Ep[2]=0.f;
    }

    // ---- pre_j (JointSE3) = E o T_offset ----
    float PR[9], Pp[3];
    compose(ER, Ep, ToR, Top, PR, Pp);

    if (active) {
        // rotated row order spreads LDS banks across lanes
        float4* dst = (float4*)&s_j[(bl * NJ + g) * 16];
#pragma unroll
        for (int r0 = 0; r0 < 4; r0++) {
            int r = (r0 + g) & 3;
            float4 v = (r < 3) ? make_float4(PR[r*3+0], PR[r*3+1], PR[r*3+2], Pp[r])
                               : make_float4(0.f, 0.f, 0.f, 1.f);
            dst[r] = v;
        }
        if ((g & 3) == 3) {   // tracked joints 3,7,...,23 -> slots 0..5
            const float4 t0 = stat[j*8+5], t1 = stat[j*8+6], t2 = stat[j*8+7];
            float TtR[9] = {t0.x,t0.y,t0.z, t1.x,t1.y,t1.z, t2.x,t2.y,t2.z};
            float Ttp[3] = {t0.w, t1.w, t2.w};
            float TR[9], Tp[3];
            compose(MR, Mp, TtR, Ttp, TR, Tp);   // post o T_track
            float4* td = (float4*)&s_t[(bl * NTRK + (g >> 2)) * 16];
#pragma unroll
            for (int r0 = 0; r0 < 4; r0++) {
                int r = (r0 + g) & 3;
                float4 v = (r < 3) ? make_float4(TR[r*3+0], TR[r*3+1], TR[r*3+2], Tp[r])
                                   : make_float4(0.f, 0.f, 0.f, 1.f);
                td[r] = v;
            }
        }
    }
    __syncthreads();

    // ---- coalesced nontemporal flush: bypass L2, full 64B lines ----
    const f4* sj4 = (const f4*)s_j;
    f4* oj = (f4*)out_joint + (size_t)blockIdx.x * (BPB * NJ * 4);
#pragma unroll
    for (int k = 0; k < 3; k++) {
        int idx = tid + 256 * k;               // 768 float4 per block
        __builtin_nontemporal_store(sj4[idx], &oj[idx]);
    }
    const f4* st4 = (const f4*)s_t;
    f4* ot = (f4*)out_track + (size_t)blockIdx.x * (BPB * NTRK * 4);
    if (tid < BPB * NTRK * 4)
        __builtin_nontemporal_store(st4[tid], &ot[tid]);   // 192 float4 per block
}

extern "C" void kernel_launch(void* const* d_in, const int* in_sizes, int n_in,
                              void* d_out, int out_size, void* d_ws, size_t ws_size,
                              hipStream_t stream) {
    const float* rev_q    = (const float*)d_in[0];
    const float* pri_q    = (const float*)d_in[1];
    const float* p_off    = (const float*)d_in[2];
    const float* rpy_off  = (const float*)d_in[3];
    const float* rev_axis = (const float*)d_in[4];
    const float* pri_axis = (const float*)d_in[5];
    const float* p_trk    = (const float*)d_in[6];
    const float* rpy_trk  = (const float*)d_in[7];

    float* out = (float*)d_out;
    float* out_track = out;                           // (B, 6, 4, 4)
    float* out_joint = out + (size_t)NB * NTRK * 16;  // (B, 24, 4, 4)
    float4* ws = (float4*)d_ws;                       // 24*8 float4 = 3 KB

    hipLaunchKernelGGL(statics_kernel, dim3(1), dim3(32), 0, stream,
                       p_off, rpy_off, rev_axis, pri_axis, p_trk, rpy_trk, ws);

    dim3 grid(NB / BPB), block(256);
    hipLaunchKernelGGL(fk_scan_kernel, grid, block, 0, stream,
                       rev_q, pri_q, (const float4*)ws, out_track, out_joint);
}

// Round 4
// 34.408 us; speedup vs baseline: 2.1719x; 2.1719x over previous
//
#include <hip/hip_runtime.h>

#define NB 65536
#define NJ 24
#define NTRK 6
#define GRP 8         // lanes per batch (24/3, no idle lanes)
#define JPL 3         // joints per lane
#define BPB 32        // batches per 256-thread block
#define PADF4 97      // float4 stride per batch in LDS (96 + 1 pad -> bank-uniform)

typedef float f4 __attribute__((ext_vector_type(4)));

__device__ __forceinline__ void rpy2R(float r, float p, float y, float* R) {
    float cr = cosf(r), sr = sinf(r);
    float cp = cosf(p), sp = sinf(p);
    float cy = cosf(y), sy = sinf(y);
    R[0] = cy * cp; R[1] = cy * sp * sr - sy * cr; R[2] = cy * sp * cr + sy * sr;
    R[3] = sy * cp; R[4] = sy * sp * sr + cy * cr; R[5] = sy * sp * cr - cy * sr;
    R[6] = -sp;     R[7] = cp * sr;                R[8] = cp * cr;
}

// C = A o B (SE3): Rc = Ra*Rb, pc = Ra*pb + pa.  C must not alias A or B.
__device__ __forceinline__ void compose(const float* Ra, const float* pa,
                                        const float* Rb, const float* pb,
                                        float* Rc, float* pc) {
#pragma unroll
    for (int i = 0; i < 3; i++) {
        float a0 = Ra[i*3+0], a1 = Ra[i*3+1], a2 = Ra[i*3+2];
        Rc[i*3+0] = a0*Rb[0] + a1*Rb[3] + a2*Rb[6];
        Rc[i*3+1] = a0*Rb[1] + a1*Rb[4] + a2*Rb[7];
        Rc[i*3+2] = a0*Rb[2] + a1*Rb[5] + a2*Rb[8];
        pc[i]     = a0*pb[0] + a1*pb[1] + a2*pb[2] + pa[i];
    }
}

// per joint j, float4 slot j*8+k: 0..2 T_offset rows|p, 3 norm axis|adot,
// 4 pri_axis, 5..7 T_track rows|p
__global__ void statics_kernel(
    const float* __restrict__ p_off,    const float* __restrict__ rpy_off,
    const float* __restrict__ rev_axis, const float* __restrict__ pri_axis,
    const float* __restrict__ p_trk,    const float* __restrict__ rpy_trk,
    float4* __restrict__ ws)
{
    int j = threadIdx.x;
    if (j >= NJ) return;
    float R[9];
    rpy2R(rpy_off[j*3+0], rpy_off[j*3+1], rpy_off[j*3+2], R);
    ws[j*8+0] = make_float4(R[0], R[1], R[2], p_off[j*3+0]);
    ws[j*8+1] = make_float4(R[3], R[4], R[5], p_off[j*3+1]);
    ws[j*8+2] = make_float4(R[6], R[7], R[8], p_off[j*3+2]);

    float ax = rev_axis[j*3+0], ay = rev_axis[j*3+1], az = rev_axis[j*3+2];
    float n = sqrtf(ax*ax + ay*ay + az*az) + 1e-8f;   // ref: axis/(norm+EPS)
    ax /= n; ay /= n; az /= n;
    ws[j*8+3] = make_float4(ax, ay, az, ax*ax + ay*ay + az*az);
    ws[j*8+4] = make_float4(pri_axis[j*3+0], pri_axis[j*3+1], pri_axis[j*3+2], 0.f);

    rpy2R(rpy_trk[j*3+0], rpy_trk[j*3+1], rpy_trk[j*3+2], R);
    ws[j*8+5] = make_float4(R[0], R[1], R[2], p_trk[j*3+0]);
    ws[j*8+6] = make_float4(R[3], R[4], R[5], p_trk[j*3+1]);
    ws[j*8+7] = make_float4(R[6], R[7], R[8], p_trk[j*3+2]);
}

__global__ __launch_bounds__(256, 3) void fk_kernel(
    const float* __restrict__ rev_q, const float* __restrict__ pri_q,
    const float4* __restrict__ stat,
    float* __restrict__ out_track, float* __restrict__ out_joint)
{
    __shared__ float4 s_stat[NJ * 8];    // 3 KB
    __shared__ f4 s_j[BPB * PADF4];      // 49.6 KB staging, exact output rows + pad

    const int tid = threadIdx.x;
    const int g   = tid & (GRP - 1);     // lane within batch (owns joints 3g..3g+2)
    const int bb  = tid >> 3;            // batch within block
    const int b   = blockIdx.x * BPB + bb;

    // q loads issued early (3 scalars each; 12.6 MB total stream)
    const float* rq = rev_q + (size_t)b * NJ + 3 * g;
    const float* pq = pri_q + (size_t)b * NJ + 3 * g;
    float qr[JPL] = {rq[0], rq[1], rq[2]};
    float qp[JPL] = {pq[0], pq[1], pq[2]};

    if (tid < NJ * 8) s_stat[tid] = stat[tid];
    __syncthreads();

    // ---- local serial pass over this lane's 3 joints (from identity) ----
    float preR[JPL][9], prep[JPL][3];    // local pre' (recorded JointSE3, pre-prefix)
    float curR[9], curp[3];              // running local product; ends as lane product
    float tR[9], tp[3];                  // local post at this lane's tracked joint
    int jt = -1;

#pragma unroll
    for (int k = 0; k < JPL; k++) {
        const int j = 3 * g + k;
        const float4 s0 = s_stat[j*8+0], s1 = s_stat[j*8+1], s2 = s_stat[j*8+2];
        const float4 s3 = s_stat[j*8+3], s4 = s_stat[j*8+4];
        float ToR[9] = {s0.x,s0.y,s0.z, s1.x,s1.y,s1.z, s2.x,s2.y,s2.z};
        float Top[3] = {s0.w, s1.w, s2.w};

        if (k == 0) {
#pragma unroll
            for (int i = 0; i < 9; i++) preR[0][i] = ToR[i];
#pragma unroll
            for (int i = 0; i < 3; i++) prep[0][i] = Top[i];
        } else {
            compose(curR, curp, ToR, Top, preR[k], prep[k]);
        }

        // joint transform: Rodrigues + prismatic
        float s = __sinf(qr[k]), c = __cosf(qr[k]), c1 = 1.0f - c;
        const float ax = s3.x, ay = s3.y, az = s3.z, adot = s3.w;
        float jR[9];
        jR[0] = 1.f + c1*(ax*ax - adot);  jR[1] = -s*az + c1*ax*ay;        jR[2] =  s*ay + c1*ax*az;
        jR[3] =  s*az + c1*ax*ay;         jR[4] = 1.f + c1*(ay*ay - adot); jR[5] = -s*ax + c1*ay*az;
        jR[6] = -s*ay + c1*ax*az;         jR[7] =  s*ax + c1*ay*az;        jR[8] = 1.f + c1*(az*az - adot);
        float v0 = qp[k]*s4.x, v1 = qp[k]*s4.y, v2 = qp[k]*s4.z;
        float jp[3];
        jp[0] = jR[0]*v0 + jR[1]*v1 + jR[2]*v2;
        jp[1] = jR[3]*v0 + jR[4]*v1 + jR[5]*v2;
        jp[2] = jR[6]*v0 + jR[7]*v1 + jR[8]*v2;

        compose(preR[k], prep[k], jR, jp, curR, curp);   // cur = pre' o Tj

        if ((j & 3) == 3) {   // lane's tracked joint (at most one per lane)
            jt = j;
#pragma unroll
            for (int i = 0; i < 9; i++) tR[i] = curR[i];
#pragma unroll
            for (int i = 0; i < 3; i++) tp[i] = curp[i];
        }
    }

    // ---- 3-step inclusive scan of lane products over 8 lanes ----
#pragma unroll
    for (int sft = 1; sft < GRP; sft <<= 1) {
        float fR[9], fp[3];
#pragma unroll
        for (int i = 0; i < 9; i++) fR[i] = __shfl_up(curR[i], sft, GRP);
#pragma unroll
        for (int i = 0; i < 3; i++) fp[i] = __shfl_up(curp[i], sft, GRP);
        if (g >= sft) {
            float nR[9], np[3];
            compose(fR, fp, curR, curp, nR, np);   // earlier lanes on the left
#pragma unroll
            for (int i = 0; i < 9; i++) curR[i] = nR[i];
#pragma unroll
            for (int i = 0; i < 3; i++) curp[i] = np[i];
        }
    }

    // ---- exclusive prefix E (identity for lane 0) ----
    float ER[9], Ep[3];
#pragma unroll
    for (int i = 0; i < 9; i++) ER[i] = __shfl_up(curR[i], 1, GRP);
#pragma unroll
    for (int i = 0; i < 3; i++) Ep[i] = __shfl_up(curp[i], 1, GRP);
    if (g == 0) {
        ER[0]=1.f; ER[1]=0.f; ER[2]=0.f; ER[3]=0.f; ER[4]=1.f; ER[5]=0.f;
        ER[6]=0.f; ER[7]=0.f; ER[8]=1.f; Ep[0]=0.f; Ep[1]=0.f; Ep[2]=0.f;
    }

    // ---- tracked output: (E o post'_t) o T_track, stored direct (row-contig) ----
    if (jt >= 0) {
        float PR[9], Pp[3];
        compose(ER, Ep, tR, tp, PR, Pp);
        const float4 t0 = s_stat[jt*8+5], t1 = s_stat[jt*8+6], t2 = s_stat[jt*8+7];
        float TtR[9] = {t0.x,t0.y,t0.z, t1.x,t1.y,t1.z, t2.x,t2.y,t2.z};
        float Ttp[3] = {t0.w, t1.w, t2.w};
        float TR[9], Tp[3];
        compose(PR, Pp, TtR, Ttp, TR, Tp);
        float4* td = (float4*)out_track + ((size_t)b * NTRK + (jt >> 2)) * 4;
        td[0] = make_float4(TR[0], TR[1], TR[2], Tp[0]);
        td[1] = make_float4(TR[3], TR[4], TR[5], Tp[1]);
        td[2] = make_float4(TR[6], TR[7], TR[8], Tp[2]);
        td[3] = make_float4(0.f, 0.f, 0.f, 1.f);
    }

    // ---- finalize pre_j = E o pre'_k, stage into LDS (natural row order) ----
#pragma unroll
    for (int k = 0; k < JPL; k++) {
        float FR[9], Fp[3];
        compose(ER, Ep, preR[k], prep[k], FR, Fp);
        f4* dst = &s_j[bb * PADF4 + (3 * g + k) * 4];
        dst[0] = (f4){FR[0], FR[1], FR[2], Fp[0]};
        dst[1] = (f4){FR[3], FR[4], FR[5], Fp[1]};
        dst[2] = (f4){FR[6], FR[7], FR[8], Fp[2]};
        dst[3] = (f4){0.f, 0.f, 0.f, 1.f};
    }
    __syncthreads();

    // ---- coalesced nontemporal flush: 12 x 1KB-per-instruction full lines ----
    f4* oj = (f4*)out_joint + (size_t)blockIdx.x * (BPB * NJ * 4);
#pragma unroll
    for (int it = 0; it < 12; it++) {
        int flat = it * 256 + tid;          // 0 .. 3071
        int bI = flat / 96;                 // magic-mul by compiler
        int rem = flat - bI * 96;
        __builtin_nontemporal_store(s_j[bI * PADF4 + rem], &oj[flat]);
    }
}

extern "C" void kernel_launch(void* const* d_in, const int* in_sizes, int n_in,
                              void* d_out, int out_size, void* d_ws, size_t ws_size,
                              hipStream_t stream) {
    const float* rev_q    = (const float*)d_in[0];
    const float* pri_q    = (const float*)d_in[1];
    const float* p_off    = (const float*)d_in[2];
    const float* rpy_off  = (const float*)d_in[3];
    const float* rev_axis = (const float*)d_in[4];
    const float* pri_axis = (const float*)d_in[5];
    const float* p_trk    = (const float*)d_in[6];
    const float* rpy_trk  = (const float*)d_in[7];

    float* out = (float*)d_out;
    float* out_track = out;                           // (B, 6, 4, 4)
    float* out_joint = out + (size_t)NB * NTRK * 16;  // (B, 24, 4, 4)
    float4* ws = (float4*)d_ws;                       // 24*8 float4 = 3 KB

    hipLaunchKernelGGL(statics_kernel, dim3(1), dim3(32), 0, stream,
                       p_off, rpy_off, rev_axis, pri_axis, p_trk, rpy_trk, ws);

    dim3 grid(NB / BPB), block(256);
    hipLaunchKernelGGL(fk_kernel, grid, block, 0, stream,
                       rev_q, pri_q, (const float4*)ws, out_track, out_joint);
}

// Round 5
// 34.233 us; speedup vs baseline: 2.1831x; 1.0051x over previous
//
#include <hip/hip_runtime.h>

#define NB 65536
#define NJ 24
#define NTRK 6
#define GRP 8         // lanes per batch (24/3, no idle lanes)
#define JPL 3         // joints per lane
#define BPB 32        // batches per 256-thread block
#define PAD3 72       // f4 per batch in LDS: 24 joints x 3 rows (bottom row constant)

typedef float f4 __attribute__((ext_vector_type(4)));

__device__ __forceinline__ void rpy2R(float r, float p, float y, float* R) {
    float cr = cosf(r), sr = sinf(r);
    float cp = cosf(p), sp = sinf(p);
    float cy = cosf(y), sy = sinf(y);
    R[0] = cy * cp; R[1] = cy * sp * sr - sy * cr; R[2] = cy * sp * cr + sy * sr;
    R[3] = sy * cp; R[4] = sy * sp * sr + cy * cr; R[5] = sy * sp * cr - cy * sr;
    R[6] = -sp;     R[7] = cp * sr;                R[8] = cp * cr;
}

// C = A o B (SE3): Rc = Ra*Rb, pc = Ra*pb + pa.  C must not alias A or B.
__device__ __forceinline__ void compose(const float* Ra, const float* pa,
                                        const float* Rb, const float* pb,
                                        float* Rc, float* pc) {
#pragma unroll
    for (int i = 0; i < 3; i++) {
        float a0 = Ra[i*3+0], a1 = Ra[i*3+1], a2 = Ra[i*3+2];
        Rc[i*3+0] = a0*Rb[0] + a1*Rb[3] + a2*Rb[6];
        Rc[i*3+1] = a0*Rb[1] + a1*Rb[4] + a2*Rb[7];
        Rc[i*3+2] = a0*Rb[2] + a1*Rb[5] + a2*Rb[8];
        pc[i]     = a0*pb[0] + a1*pb[1] + a2*pb[2] + pa[i];
    }
}

__global__ __launch_bounds__(256, 4) void fk_kernel(
    const float* __restrict__ rev_q,    const float* __restrict__ pri_q,
    const float* __restrict__ p_off,    const float* __restrict__ rpy_off,
    const float* __restrict__ rev_axis, const float* __restrict__ pri_axis,
    const float* __restrict__ p_trk,    const float* __restrict__ rpy_trk,
    float* __restrict__ out_track, float* __restrict__ out_joint)
{
    // per joint j, slot j*8+k: 0..2 T_offset rows|p, 3 norm axis|adot,
    // 4 pri_axis, 5..7 T_track rows|p
    __shared__ float4 s_stat[NJ * 8];   // 3 KB
    __shared__ f4 s_j[BPB * PAD3];      // 36 KB (3 rows per matrix)

    const int tid = threadIdx.x;
    const int g   = tid & (GRP - 1);    // lane within batch (owns joints 3g..3g+2)
    const int bb  = tid >> 3;           // batch within block
    const int b   = blockIdx.x * BPB + bb;

    // q loads issued first (stream-once, 12.6 MB total)
    const float* rq = rev_q + (size_t)b * NJ + 3 * g;
    const float* pq = pri_q + (size_t)b * NJ + 3 * g;
    float qr[JPL] = {rq[0], rq[1], rq[2]};
    float qp[JPL] = {pq[0], pq[1], pq[2]};

    // ---- per-block statics (tiny, L2-hot after first blocks) ----
    if (tid < NJ) {
        const int j = tid;
        float R[9];
        rpy2R(rpy_off[j*3+0], rpy_off[j*3+1], rpy_off[j*3+2], R);
        s_stat[j*8+0] = make_float4(R[0], R[1], R[2], p_off[j*3+0]);
        s_stat[j*8+1] = make_float4(R[3], R[4], R[5], p_off[j*3+1]);
        s_stat[j*8+2] = make_float4(R[6], R[7], R[8], p_off[j*3+2]);

        float ax = rev_axis[j*3+0], ay = rev_axis[j*3+1], az = rev_axis[j*3+2];
        float n = sqrtf(ax*ax + ay*ay + az*az) + 1e-8f;   // ref: axis/(norm+EPS)
        ax /= n; ay /= n; az /= n;
        s_stat[j*8+3] = make_float4(ax, ay, az, ax*ax + ay*ay + az*az);
        s_stat[j*8+4] = make_float4(pri_axis[j*3+0], pri_axis[j*3+1], pri_axis[j*3+2], 0.f);

        rpy2R(rpy_trk[j*3+0], rpy_trk[j*3+1], rpy_trk[j*3+2], R);
        s_stat[j*8+5] = make_float4(R[0], R[1], R[2], p_trk[j*3+0]);
        s_stat[j*8+6] = make_float4(R[3], R[4], R[5], p_trk[j*3+1]);
        s_stat[j*8+7] = make_float4(R[6], R[7], R[8], p_trk[j*3+2]);
    }
    __syncthreads();

    // ---- local serial pass over this lane's 3 joints (from identity) ----
    float preR[JPL][9], prep[JPL][3];   // local pre' (pre-prefix JointSE3)
    float curR[9], curp[3];             // running local product -> lane product
    float tR[9], tp[3];                 // local post at this lane's tracked joint
    int jt = -1;

#pragma unroll
    for (int k = 0; k < JPL; k++) {
        const int j = 3 * g + k;
        const float4 s0 = s_stat[j*8+0], s1 = s_stat[j*8+1], s2 = s_stat[j*8+2];
        const float4 s3 = s_stat[j*8+3], s4 = s_stat[j*8+4];
        float ToR[9] = {s0.x,s0.y,s0.z, s1.x,s1.y,s1.z, s2.x,s2.y,s2.z};
        float Top[3] = {s0.w, s1.w, s2.w};

        if (k == 0) {
#pragma unroll
            for (int i = 0; i < 9; i++) preR[0][i] = ToR[i];
#pragma unroll
            for (int i = 0; i < 3; i++) prep[0][i] = Top[i];
        } else {
            compose(curR, curp, ToR, Top, preR[k], prep[k]);
        }

        // joint transform: Rodrigues + prismatic
        float s = __sinf(qr[k]), c = __cosf(qr[k]), c1 = 1.0f - c;
        const float ax = s3.x, ay = s3.y, az = s3.z, adot = s3.w;
        float jR[9];
        jR[0] = 1.f + c1*(ax*ax - adot);  jR[1] = -s*az + c1*ax*ay;        jR[2] =  s*ay + c1*ax*az;
        jR[3] =  s*az + c1*ax*ay;         jR[4] = 1.f + c1*(ay*ay - adot); jR[5] = -s*ax + c1*ay*az;
        jR[6] = -s*ay + c1*ax*az;         jR[7] =  s*ax + c1*ay*az;        jR[8] = 1.f + c1*(az*az - adot);
        float v0 = qp[k]*s4.x, v1 = qp[k]*s4.y, v2 = qp[k]*s4.z;
        float jp[3];
        jp[0] = jR[0]*v0 + jR[1]*v1 + jR[2]*v2;
        jp[1] = jR[3]*v0 + jR[4]*v1 + jR[5]*v2;
        jp[2] = jR[6]*v0 + jR[7]*v1 + jR[8]*v2;

        compose(preR[k], prep[k], jR, jp, curR, curp);   // cur = pre' o Tj

        if ((j & 3) == 3) {   // lane's tracked joint (at most one per lane)
            jt = j;
#pragma unroll
            for (int i = 0; i < 9; i++) tR[i] = curR[i];
#pragma unroll
            for (int i = 0; i < 3; i++) tp[i] = curp[i];
        }
    }

    // ---- 3-step inclusive scan of lane products over 8 lanes ----
#pragma unroll
    for (int sft = 1; sft < GRP; sft <<= 1) {
        float fR[9], fp[3];
#pragma unroll
        for (int i = 0; i < 9; i++) fR[i] = __shfl_up(curR[i], sft, GRP);
#pragma unroll
        for (int i = 0; i < 3; i++) fp[i] = __shfl_up(curp[i], sft, GRP);
        if (g >= sft) {
            float nR[9], np[3];
            compose(fR, fp, curR, curp, nR, np);   // earlier lanes on the left
#pragma unroll
            for (int i = 0; i < 9; i++) curR[i] = nR[i];
#pragma unroll
            for (int i = 0; i < 3; i++) curp[i] = np[i];
        }
    }

    // ---- exclusive prefix E (identity for lane 0) ----
    float ER[9], Ep[3];
#pragma unroll
    for (int i = 0; i < 9; i++) ER[i] = __shfl_up(curR[i], 1, GRP);
#pragma unroll
    for (int i = 0; i < 3; i++) Ep[i] = __shfl_up(curp[i], 1, GRP);
    if (g == 0) {
        ER[0]=1.f; ER[1]=0.f; ER[2]=0.f; ER[3]=0.f; ER[4]=1.f; ER[5]=0.f;
        ER[6]=0.f; ER[7]=0.f; ER[8]=1.f; Ep[0]=0.f; Ep[1]=0.f; Ep[2]=0.f;
    }

    // ---- tracked output: (E o post'_t) o T_track, stored direct ----
    if (jt >= 0) {
        float PR[9], Pp[3];
        compose(ER, Ep, tR, tp, PR, Pp);
        const float4 t0 = s_stat[jt*8+5], t1 = s_stat[jt*8+6], t2 = s_stat[jt*8+7];
        float TtR[9] = {t0.x,t0.y,t0.z, t1.x,t1.y,t1.z, t2.x,t2.y,t2.z};
        float Ttp[3] = {t0.w, t1.w, t2.w};
        float TR[9], Tp[3];
        compose(PR, Pp, TtR, Ttp, TR, Tp);
        float4* td = (float4*)out_track + ((size_t)b * NTRK + (jt >> 2)) * 4;
        td[0] = make_float4(TR[0], TR[1], TR[2], Tp[0]);
        td[1] = make_float4(TR[3], TR[4], TR[5], Tp[1]);
        td[2] = make_float4(TR[6], TR[7], TR[8], Tp[2]);
        td[3] = make_float4(0.f, 0.f, 0.f, 1.f);
    }

    // ---- finalize pre_j = E o pre'_k, stage 3 rows into LDS ----
#pragma unroll
    for (int k = 0; k < JPL; k++) {
        float FR[9], Fp[3];
        compose(ER, Ep, preR[k], prep[k], FR, Fp);
        f4* dst = &s_j[bb * PAD3 + (3 * g + k) * 3];
        dst[0] = (f4){FR[0], FR[1], FR[2], Fp[0]};
        dst[1] = (f4){FR[3], FR[4], FR[5], Fp[1]};
        dst[2] = (f4){FR[6], FR[7], FR[8], Fp[2]};
    }
    __syncthreads();

    // ---- coalesced nontemporal flush; constant bottom rows from immediates ----
    f4* oj = (f4*)out_joint + (size_t)blockIdx.x * (BPB * NJ * 4);
#pragma unroll
    for (int it = 0; it < 12; it++) {
        int flat = it * 256 + tid;          // 0 .. 3071 output f4 index
        int bI = flat / 96;                 // batch within block (magic-mul)
        int rem = flat - bI * 96;
        int r = rem & 3;                    // row within 4x4
        int jj = rem >> 2;                  // joint
        f4 v;
        if (r == 3) v = (f4){0.f, 0.f, 0.f, 1.f};
        else        v = s_j[bI * PAD3 + jj * 3 + r];
        __builtin_nontemporal_store(v, &oj[flat]);
    }
}

extern "C" void kernel_launch(void* const* d_in, const int* in_sizes, int n_in,
                              void* d_out, int out_size, void* d_ws, size_t ws_size,
                              hipStream_t stream) {
    const float* rev_q    = (const float*)d_in[0];
    const float* pri_q    = (const float*)d_in[1];
    const float* p_off    = (const float*)d_in[2];
    const float* rpy_off  = (const float*)d_in[3];
    const float* rev_axis = (const float*)d_in[4];
    const float* pri_axis = (const float*)d_in[5];
    const float* p_trk    = (const float*)d_in[6];
    const float* rpy_trk  = (const float*)d_in[7];

    float* out = (float*)d_out;
    float* out_track = out;                           // (B, 6, 4, 4)
    float* out_joint = out + (size_t)NB * NTRK * 16;  // (B, 24, 4, 4)

    dim3 grid(NB / BPB), block(256);
    hipLaunchKernelGGL(fk_kernel, grid, block, 0, stream,
                       rev_q, pri_q, p_off, rpy_off, rev_axis, pri_axis,
                       p_trk, rpy_trk, out_track, out_joint);
}